// Round 7
// baseline (133.825 us; speedup 1.0000x reference)
//
#include <hip/hip_runtime.h>
#include <cstdint>
#include <cstddef>

// out[64,197,768] = concat(cls, patchify(images[64,3,224,224]) @ W^T + b)
// R7: hybrid of r5+r6.
//  - A: patchify-gathered fp32->bf16 into LDS per K-half (48.5 KB, PITCH=388
//    proven 0-conflict in r5). No A prepass. 3 barriers per block total.
//  - B: read directly from FRAGMENT-MAJOR bf16 Wf (r6 layout) as lane-
//    contiguous 1KB loads; within-block wave pairs share b-frags via L1.
//  - Block 256 thr = 4 waves (2mg x 2ng of 32m x 64n) = 64m x 128n tile.
//    Grid 1176 XCD-swizzled. LDS 49.8KB -> 3 blocks/CU (12 waves/CU).
#define PITCH 388

typedef float  f32x4  __attribute__((ext_vector_type(4)));
typedef __bf16 bf16x8 __attribute__((ext_vector_type(8)));

// ---------------- Prep: W fp32 -> fragment-major bf16 Wf + cls rows ----------------
#define W_BLOCKS   288   // 48 ntiles * 24 ksteps * 64 lanes / 256
#define CLS_BLOCKS 48
#define WF_ELEMS   (48*24*64*8)

__global__ __launch_bounds__(256) void prep_kernel(
    const float* __restrict__ Wm, const float* __restrict__ cls,
    float* __restrict__ out, __bf16* __restrict__ Wf) {
  const int bid = blockIdx.x, tid = threadIdx.x;
  if (bid < W_BLOCKS) {
    const int u = bid * 256 + tid;
    const int l = u & 63, f = u >> 6;
    const int ntile = f / 24, kstep = f - ntile * 24;
    const int h = ntile * 16 + (l & 15);
    const int k = kstep * 32 + (l >> 4) * 8;
    const float* g = Wm + (size_t)h * 768 + k;
    const f32x4 v0 = ((const f32x4*)g)[0];
    const f32x4 v1 = ((const f32x4*)g)[1];
    bf16x8 o;
    o[0]=(__bf16)v0[0]; o[1]=(__bf16)v0[1]; o[2]=(__bf16)v0[2]; o[3]=(__bf16)v0[3];
    o[4]=(__bf16)v1[0]; o[5]=(__bf16)v1[1]; o[6]=(__bf16)v1[2]; o[7]=(__bf16)v1[3];
    *(bf16x8*)(Wf + (size_t)u * 8) = o;
  } else {
    const int t  = (bid - W_BLOCKS) * 256 + tid;
    const int bb = t / 192;
    const int r  = t - bb * 192;
    *(float4*)(out + (size_t)bb * 197 * 768 + r * 4) = *(const float4*)(cls + r * 4);
  }
}

// ---------------- Fused patchify + GEMM ----------------
#define MFMA __builtin_amdgcn_mfma_f32_16x16x32_bf16

__device__ __forceinline__ void cvt_store(__bf16* dst, const f32x4 a, const f32x4 b) {
  bf16x8 o;
  o[0]=(__bf16)a[0]; o[1]=(__bf16)a[1]; o[2]=(__bf16)a[2]; o[3]=(__bf16)a[3];
  o[4]=(__bf16)b[0]; o[5]=(__bf16)b[1]; o[6]=(__bf16)b[2]; o[7]=(__bf16)b[3];
  *(bf16x8*)dst = o;
}

__global__ __launch_bounds__(256, 3) void gemm_kernel(
    const float* __restrict__ images, const __bf16* __restrict__ Wf,
    const float* __restrict__ bias, float* __restrict__ out) {
  __shared__ __bf16 As[64 * PITCH + 64];   // 49,792 B -> 3 blocks/CU

  const int tid = threadIdx.x;
  // XCD swizzle: consecutive g share an XCD -> an mblk's 6 n-siblings reuse
  // the same image rows from that XCD's L2.
  const int g    = (blockIdx.x & 7) * 147 + (blockIdx.x >> 3);
  const int mblk = g / 6, nblk = g - mblk * 6;
  const int wave = tid >> 6, lane = tid & 63;
  const int mg = wave & 1, ng = wave >> 1;   // wave = 32m x 64n
  const int lrow = lane & 15, lq = lane >> 4;

  // ---- A staging addressing: thread owns row arow, k-chunks s0+4i (16 elems) ----
  const int arow = tid & 63;
  const int s0   = tid >> 6;                 // 0..3
  const int m  = mblk * 64 + arow;
  const int bb = m / 196, p = m - bb * 196;
  const int pi = p / 14,  pj = p - pi * 14;
  const float* rowbase = images + ((size_t)(bb * 3) * 224 + (size_t)(pi * 16)) * 224 + pj * 16;

  // ---- B fragment pointers (unit = bf16x8 = 16B; frag = 64 units) ----
  const int nt0 = nblk * 8 + ng * 4;
  const bf16x8* pbb[4];
#pragma unroll
  for (int j = 0; j < 4; ++j)
    pbb[j] = (const bf16x8*)Wf + (size_t)(nt0 + j) * 24 * 64 + lane;

  const __bf16* aLbase = As + (mg * 32 + lrow) * PITCH + lq * 8;

  f32x4 acc[2][4] = {};

  for (int kh = 0; kh < 2; ++kh) {
    if (kh) __syncthreads();   // previous half fully consumed before overwrite

    // ---- stage K-half kh: 64 rows x 384 k ----
#pragma unroll
    for (int i = 0; i < 6; ++i) {
      const int s  = s0 + 4 * i;           // 0..23
      const int kc = kh * 24 + s;          // global 16-k chunk 0..47
      const int c  = kc >> 4, ph = kc & 15;
      const float* gp = rowbase + ((size_t)c * 224 + ph) * 224;
      const f32x4 v0 = ((const f32x4*)gp)[0];
      const f32x4 v1 = ((const f32x4*)gp)[1];
      const f32x4 v2 = ((const f32x4*)gp)[2];
      const f32x4 v3 = ((const f32x4*)gp)[3];
      __bf16* dst = &As[arow * PITCH + s * 16];
      cvt_store(dst,     v0, v1);
      cvt_store(dst + 8, v2, v3);
    }
    __syncthreads();

    // ---- compute 12 k-steps from this half; barrier-free; dist-1 prefetch ----
    const int ksg0 = kh * 12;
    bf16x8 a0 = *(const bf16x8*)(aLbase);
    bf16x8 a1 = *(const bf16x8*)(aLbase + 16 * PITCH);
    bf16x8 b0 = pbb[0][(size_t)ksg0 * 64];
    bf16x8 b1 = pbb[1][(size_t)ksg0 * 64];
    bf16x8 b2 = pbb[2][(size_t)ksg0 * 64];
    bf16x8 b3 = pbb[3][(size_t)ksg0 * 64];
#pragma unroll
    for (int ksl = 0; ksl < 12; ++ksl) {
      bf16x8 na0, na1, nb0, nb1, nb2, nb3;
      if (ksl < 11) {
        const int nk = ksl + 1;
        na0 = *(const bf16x8*)(aLbase + nk * 32);
        na1 = *(const bf16x8*)(aLbase + 16 * PITCH + nk * 32);
        nb0 = pbb[0][(size_t)(ksg0 + nk) * 64];
        nb1 = pbb[1][(size_t)(ksg0 + nk) * 64];
        nb2 = pbb[2][(size_t)(ksg0 + nk) * 64];
        nb3 = pbb[3][(size_t)(ksg0 + nk) * 64];
      }
      acc[0][0] = MFMA(a0, b0, acc[0][0], 0, 0, 0);
      acc[0][1] = MFMA(a0, b1, acc[0][1], 0, 0, 0);
      acc[0][2] = MFMA(a0, b2, acc[0][2], 0, 0, 0);
      acc[0][3] = MFMA(a0, b3, acc[0][3], 0, 0, 0);
      acc[1][0] = MFMA(a1, b0, acc[1][0], 0, 0, 0);
      acc[1][1] = MFMA(a1, b1, acc[1][1], 0, 0, 0);
      acc[1][2] = MFMA(a1, b2, acc[1][2], 0, 0, 0);
      acc[1][3] = MFMA(a1, b3, acc[1][3], 0, 0, 0);
      if (ksl < 11) { a0 = na0; a1 = na1; b0 = nb0; b1 = nb1; b2 = nb2; b3 = nb3; }
    }
  }

  // ---- epilogue: C/D layout col=lane&15 (=n), row=(lane>>4)*4+r (=m) ----
#pragma unroll
  for (int j = 0; j < 4; ++j) {
    const int h  = (nt0 + j) * 16 + lrow;
    const float bv = bias[h];
#pragma unroll
    for (int i = 0; i < 2; ++i) {
      const int mb = mblk * 64 + mg * 32 + i * 16 + lq * 4;
#pragma unroll
      for (int r = 0; r < 4; ++r) {
        const int mm  = mb + r;
        const int bb2 = mm / 196, p2 = mm - bb2 * 196;
        out[(size_t)(bb2 * 197 + 1 + p2) * 768 + h] = acc[i][j][r] + bv;
      }
    }
  }
}

extern "C" void kernel_launch(void* const* d_in, const int* in_sizes, int n_in,
                              void* d_out, int out_size, void* d_ws, size_t ws_size,
                              hipStream_t stream) {
  const float* images = (const float*)d_in[0];  // [64,3,224,224]
  const float* Wm     = (const float*)d_in[1];  // [768,768]
  const float* b      = (const float*)d_in[2];  // [768]
  const float* cls    = (const float*)d_in[3];  // [1,768]
  float* out = (float*)d_out;                   // [64,197,768]
  __bf16* Wf = (__bf16*)d_ws;                   // 1.18 MB fragment-major W
  (void)in_sizes; (void)n_in; (void)out_size; (void)ws_size;

  prep_kernel<<<W_BLOCKS + CLS_BLOCKS, 256, 0, stream>>>(Wm, cls, out, Wf);
  gemm_kernel<<<196 * 6, 256, 0, stream>>>(images, Wf, b, out);
}